// Round 5
// baseline (1289.041 us; speedup 1.0000x reference)
//
#include <hip/hip_runtime.h>
#include <hip/hip_bf16.h>
#include <math.h>

#define HW   65536   // 256*256
#define NPIX 524288  // 8*65536
#define NB   8
#define NT   6
#define NC   48      // nt*nb combined channels
#define DIM  64
#define EE   128
#define KSTEPS 14    // K = 9 taps * 48 ch = 432, padded to 448 = 14 * 32
#define KVALID 432
#define COLS 130

typedef short bf16x8 __attribute__((ext_vector_type(8)));
typedef float f32x4  __attribute__((ext_vector_type(4)));

__device__ __forceinline__ float gelu_exact(float v) {
    return 0.5f * v * (1.0f + erff(v * 0.70710678118654752f));
}

__device__ __forceinline__ unsigned pack_bf16(float v0, float v1) {
    __hip_bfloat16 h0 = __float2bfloat16(v0);
    __hip_bfloat16 h1 = __float2bfloat16(v1);
    return (unsigned)(*(unsigned short*)&h0) | ((unsigned)(*(unsigned short*)&h1) << 16);
}

// ---------------- Kernel A: fold prompt into conv weights, fragment-ordered bf16 ----
// WfB flat index = ((kstep*8 + ob)*64 + lane)*8 + j   (bf16)
// A[o][k]: o = ob*16 + (lane&15); k = kstep*32 + (lane>>4)*8 + j
// k -> tap = k/48 (dy=tap/3, dx=tap%3), tk = k%48 ; zero for k>=432
__global__ __launch_bounds__(256) void fold_weights_kernel(
    const float* __restrict__ conv_w,   // [128][128][3][3]
    const float* __restrict__ prompt,   // [6][8][128]
    unsigned short* __restrict__ WfB)   // [14][8][64][8] bf16
{
    int f = blockIdx.x * 256 + threadIdx.x;   // 0 .. 57343
    int j    = f & 7;
    int lane = (f >> 3) & 63;
    int ob   = (f >> 9) & 7;
    int ks   = f >> 12;

    int o = ob * 16 + (lane & 15);
    int k = ks * 32 + ((lane >> 4) << 3) + j;

    float acc = 0.f;
    if (k < KVALID) {
        int tap = k / 48;
        int tk  = k - tap * 48;
        int dy = tap / 3;
        int dx = tap - dy * 3;
        const float* pw = conv_w + ((size_t)o * EE) * 9 + dy * 3 + dx;
        const float* pp = prompt + (size_t)tk * EE;
        #pragma unroll 4
        for (int e = 0; e < EE; ++e)
            acc += pw[(size_t)e * 9] * pp[e];
    }
    __hip_bfloat16 h = __float2bfloat16(acc);
    WfB[f] = *(unsigned short*)&h;
}

// ---------------- Kernel B: routing -> c2[6 chunk][pixel] (uint4 = 8 bf16 ch) ----
// 2 pixels/thread, float2 loads, 16-deep explicit load batches,
// shuffle-redistributed contiguous 1KB stores.
__global__ __launch_bounds__(256, 4) void routing_kernel(
    const float* __restrict__ x,      // [8][64][256][256]
    const float* __restrict__ flux,   // [8][128][256][256]
    const float* __restrict__ b1w, const float* __restrict__ b1b,
    const float* __restrict__ b2w, const float* __restrict__ b2b,
    const float* __restrict__ t1w, const float* __restrict__ t1b,
    const float* __restrict__ t2w, const float* __restrict__ t2b,
    uint4* __restrict__ c2)           // [6][NPIX] 16B chunks
{
    __shared__ float s_b1w[DIM * 8];   // [ci][j] transposed
    __shared__ float s_t1w[EE * 8];    // [ci][j] transposed, j<6 padded with 0
    __shared__ float s_b2w[64];
    __shared__ float s_t2w[36];
    __shared__ float s_b1b[8], s_b2b[8], s_t1b[8], s_t2b[8];

    int tid = threadIdx.x;
    for (int i = tid; i < DIM * 8; i += 256) {
        int ci = i >> 3, j = i & 7;
        s_b1w[i] = b1w[j * DIM + ci];
    }
    for (int i = tid; i < EE * 8; i += 256) {
        int ci = i >> 3, j = i & 7;
        s_t1w[i] = (j < NT) ? t1w[j * EE + ci] : 0.f;
    }
    if (tid < 64) s_b2w[tid] = b2w[tid];
    if (tid < 36) s_t2w[tid] = t2w[tid];
    if (tid < 8) {
        s_b1b[tid] = b1b[tid];
        s_b2b[tid] = b2b[tid];
        s_t1b[tid] = (tid < NT) ? t1b[tid] : 0.f;
        s_t2b[tid] = (tid < NT) ? t2b[tid] : 0.f;
    }
    __syncthreads();

    int gid = blockIdx.x * 256 + tid;      // 0 .. 262143 ; pixels 2*gid, 2*gid+1
    int b   = gid >> 15;
    int yx  = (gid << 1) & (HW - 1);

    // ---- MLP2 on flux (128 -> 6), nan->0, 2 pixels, 16-deep batches ----
    float t0[6], t1[6];
    #pragma unroll
    for (int j = 0; j < NT; ++j) { t0[j] = s_t1b[j]; t1[j] = s_t1b[j]; }
    const float* fp = flux + (size_t)b * EE * HW + yx;
    for (int cb = 0; cb < EE; cb += 16) {
        float2 v[16];
        #pragma unroll
        for (int u = 0; u < 16; ++u)
            v[u] = *(const float2*)(fp + (size_t)(cb + u) * HW);
        #pragma unroll
        for (int u = 0; u < 16; ++u) {
            float v0 = v[u].x; v0 = (v0 == v0) ? v0 : 0.f;
            float v1 = v[u].y; v1 = (v1 == v1) ? v1 : 0.f;
            float4 wA = *(const float4*)&s_t1w[(cb + u) * 8];
            float2 wB = *(const float2*)&s_t1w[(cb + u) * 8 + 4];
            t0[0] += v0 * wA.x; t1[0] += v1 * wA.x;
            t0[1] += v0 * wA.y; t1[1] += v1 * wA.y;
            t0[2] += v0 * wA.z; t1[2] += v1 * wA.z;
            t0[3] += v0 * wA.w; t1[3] += v1 * wA.w;
            t0[4] += v0 * wB.x; t1[4] += v1 * wB.x;
            t0[5] += v0 * wB.y; t1[5] += v1 * wB.y;
        }
    }

    // ---- MLP1 on x (64 -> 8), 2 pixels, 16-deep batches ----
    float a0[8], a1[8];
    #pragma unroll
    for (int j = 0; j < 8; ++j) { a0[j] = s_b1b[j]; a1[j] = s_b1b[j]; }
    const float* xp = x + (size_t)b * DIM * HW + yx;
    for (int cb = 0; cb < DIM; cb += 16) {
        float2 v[16];
        #pragma unroll
        for (int u = 0; u < 16; ++u)
            v[u] = *(const float2*)(xp + (size_t)(cb + u) * HW);
        #pragma unroll
        for (int u = 0; u < 16; ++u) {
            float v0 = v[u].x;
            float v1 = v[u].y;
            float4 wa = *(const float4*)&s_b1w[(cb + u) * 8];
            float4 wb = *(const float4*)&s_b1w[(cb + u) * 8 + 4];
            a0[0] += v0 * wa.x; a1[0] += v1 * wa.x;
            a0[1] += v0 * wa.y; a1[1] += v1 * wa.y;
            a0[2] += v0 * wa.z; a1[2] += v1 * wa.z;
            a0[3] += v0 * wa.w; a1[3] += v1 * wa.w;
            a0[4] += v0 * wb.x; a1[4] += v1 * wb.x;
            a0[5] += v0 * wb.y; a1[5] += v1 * wb.y;
            a0[6] += v0 * wb.z; a1[6] += v1 * wb.z;
            a0[7] += v0 * wb.w; a1[7] += v1 * wb.w;
        }
    }

    // ---- finish task (softmax over 6) for both pixels ----
    float task[2][6];
    #pragma unroll
    for (int p = 0; p < 2; ++p) {
        float gt[6];
        #pragma unroll
        for (int j = 0; j < NT; ++j) gt[j] = gelu_exact(p ? t1[j] : t0[j]);
        float tv[6];
        #pragma unroll
        for (int i = 0; i < NT; ++i) {
            float s = s_t2b[i];
            #pragma unroll
            for (int j = 0; j < NT; ++j) s += gt[j] * s_t2w[i * 6 + j];
            tv[i] = s;
        }
        float m = tv[0];
        #pragma unroll
        for (int i = 1; i < NT; ++i) m = fmaxf(m, tv[i]);
        float s = 0.f;
        #pragma unroll
        for (int i = 0; i < NT; ++i) { tv[i] = expf(tv[i] - m); s += tv[i]; }
        float inv = 1.f / s;
        #pragma unroll
        for (int i = 0; i < NT; ++i) task[p][i] = tv[i] * inv;
    }

    // ---- finish basis (softmax over 8) for both pixels ----
    float basis[2][8];
    #pragma unroll
    for (int p = 0; p < 2; ++p) {
        float g[8];
        #pragma unroll
        for (int j = 0; j < 8; ++j) g[j] = gelu_exact(p ? a1[j] : a0[j]);
        float bv[8];
        #pragma unroll
        for (int i = 0; i < 8; ++i) {
            float s = s_b2b[i];
            #pragma unroll
            for (int j = 0; j < 8; ++j) s += g[j] * s_b2w[i * 8 + j];
            bv[i] = s;
        }
        float m = bv[0];
        #pragma unroll
        for (int i = 1; i < 8; ++i) m = fmaxf(m, bv[i]);
        float s = 0.f;
        #pragma unroll
        for (int i = 0; i < 8; ++i) { bv[i] = expf(bv[i] - m); s += bv[i]; }
        float inv = 1.f / s;
        #pragma unroll
        for (int i = 0; i < 8; ++i) basis[p][i] = bv[i] * inv;
    }

    // ---- shuffle-redistribute so each store instruction is 1KB contiguous ----
    // wave covers pixels [wbase, wbase+128); lane L stores pixel wbase+L (A)
    // and wbase+64+L (B). Owner of pixel wbase+q is lane q>>1, slot q&1.
    int lane = tid & 63;
    int srcA = lane >> 1;
    int srcB = 32 + (lane >> 1);
    bool odd = lane & 1;

    float tA[6], tB[6], bA[8], bB[8];
    #pragma unroll
    for (int j = 0; j < NT; ++j) {
        float p0 = __shfl(task[0][j], srcA, 64);
        float p1 = __shfl(task[1][j], srcA, 64);
        tA[j] = odd ? p1 : p0;
        float q0 = __shfl(task[0][j], srcB, 64);
        float q1 = __shfl(task[1][j], srcB, 64);
        tB[j] = odd ? q1 : q0;
    }
    #pragma unroll
    for (int k = 0; k < 8; ++k) {
        float p0 = __shfl(basis[0][k], srcA, 64);
        float p1 = __shfl(basis[1][k], srcA, 64);
        bA[k] = odd ? p1 : p0;
        float q0 = __shfl(basis[0][k], srcB, 64);
        float q1 = __shfl(basis[1][k], srcB, 64);
        bB[k] = odd ? q1 : q0;
    }

    int wbase = (gid & ~63) * 2;    // wave's first pixel
    #pragma unroll
    for (int j = 0; j < 6; ++j) {
        uint4 qa, qb;
        qa.x = pack_bf16(tA[j] * bA[0], tA[j] * bA[1]);
        qa.y = pack_bf16(tA[j] * bA[2], tA[j] * bA[3]);
        qa.z = pack_bf16(tA[j] * bA[4], tA[j] * bA[5]);
        qa.w = pack_bf16(tA[j] * bA[6], tA[j] * bA[7]);
        qb.x = pack_bf16(tB[j] * bB[0], tB[j] * bB[1]);
        qb.y = pack_bf16(tB[j] * bB[2], tB[j] * bB[3]);
        qb.z = pack_bf16(tB[j] * bB[4], tB[j] * bB[5]);
        qb.w = pack_bf16(tB[j] * bB[6], tB[j] * bB[7]);
        c2[(size_t)j * NPIX + wbase + lane]      = qa;
        c2[(size_t)j * NPIX + wbase + 64 + lane] = qb;
    }
}

// ---------------- Kernel C: implicit-GEMM 3x3 conv via bf16 MFMA, K=448 ----------------
// grid 4096 = b(8) * y(256) * xstrip(2); block 256 = 4 waves
// block tile: M=128 out-ch  x  N=128 pixels (one row strip)
__global__ __launch_bounds__(256, 3) void conv_kernel(
    const uint4* __restrict__ c2,           // [6][NPIX] 16B chunks
    const unsigned short* __restrict__ WfB, // [14][8][64][8] bf16 fragment-ordered
    float* __restrict__ out)                // [8][128][256][256] f32
{
    __shared__ uint4 tile4[3120];   // [3][130][64ch] bf16, XOR-swizzled (49,920 B)

    int bid = blockIdx.x;
    int s = bid & 1;
    int y = (bid >> 1) & 255;
    int b = bid >> 9;
    int x0 = s << 7;
    int tid = threadIdx.x;

    // zero-fill (covers ch 48..63 padding and image borders)
    #pragma unroll 4
    for (int i = tid; i < 3120; i += 256)
        tile4[i] = make_uint4(0u, 0u, 0u, 0u);
    __syncthreads();

    // stage c halo tile: 3 rows x 6 chunks x 130 cols (col innermost -> coalesced)
    for (int idx = tid; idx < 2340; idx += 256) {
        int dyc = idx / 130;
        int col = idx - dyc * 130;
        int dy  = dyc / 6;
        int ch  = dyc - dy * 6;
        int gy = y + dy - 1;
        int gx = x0 - 1 + col;
        if ((unsigned)gy < 256u && (unsigned)gx < 256u) {
            uint4 v = c2[(size_t)ch * NPIX + (((size_t)b << 16) + (gy << 8) + gx)];
            int lb = ((dy * COLS + col) << 7) + (ch << 4);
            lb ^= (col & 7) << 4;
            tile4[lb >> 4] = v;
        }
    }
    __syncthreads();

    int lane = tid & 63;
    int wv = tid >> 6;
    int wm = wv & 1;
    int wn = wv >> 1;
    int o0 = wm << 6;
    int nbase = wn << 2;          // N-group base (of 16-pixel groups)
    int lrow = lane & 15;         // m (for A/D) and n (for B/D)
    int lk   = lane >> 4;         // k sub-block

    f32x4 acc[4][4];
    #pragma unroll
    for (int mi = 0; mi < 4; ++mi)
        #pragma unroll
        for (int ni = 0; ni < 4; ++ni)
            acc[mi][ni] = (f32x4){0.f, 0.f, 0.f, 0.f};

    const char* tbase = (const char*)tile4;

    #pragma unroll
    for (int ks = 0; ks < KSTEPS; ++ks) {
        bf16x8 a[4];
        #pragma unroll
        for (int mi = 0; mi < 4; ++mi)
            a[mi] = *(const bf16x8*)(WfB + ((size_t)((ks * 8) + wm * 4 + mi) * 64 + lane) * 8);

        // k0 = ks*32 + lk*8 ; tap = k0/48 (clamped), ch = k0 - tap*48
        int k0 = ks * 32 + (lk << 3);
        int tap = k0 / 48;
        if (tap > 8) tap = 8;        // k>=432 pad: lands in zeroed ch48..63 region
        int ch = k0 - tap * 48;
        int dy = tap / 3;
        int dx = tap - dy * 3;

        #pragma unroll
        for (int ni = 0; ni < 4; ++ni) {
            int col = ((nbase + ni) << 4) + lrow + dx;
            int lb = ((dy * COLS + col) << 7) + (ch << 1);
            lb ^= (col & 7) << 4;
            bf16x8 bfr = *(const bf16x8*)(tbase + lb);
            #pragma unroll
            for (int mi = 0; mi < 4; ++mi)
                acc[mi][ni] = __builtin_amdgcn_mfma_f32_16x16x32_bf16(a[mi], bfr, acc[mi][ni], 0, 0, 0);
        }
    }

    // D layout: col = lane&15 (pixel), row = (lane>>4)*4 + r (out channel)
    int orow = lk << 2;
    #pragma unroll
    for (int mi = 0; mi < 4; ++mi) {
        #pragma unroll
        for (int ni = 0; ni < 4; ++ni) {
            int o = o0 + mi * 16 + orow;
            int xx = x0 + ((nbase + ni) << 4) + lrow;
            float* op = out + (((size_t)(b * 128 + o)) << 16) + (y << 8) + xx;
            #pragma unroll
            for (int r = 0; r < 4; ++r)
                op[(size_t)r << 16] = acc[mi][ni][r];
        }
    }
}

extern "C" void kernel_launch(void* const* d_in, const int* in_sizes, int n_in,
                              void* d_out, int out_size, void* d_ws, size_t ws_size,
                              hipStream_t stream) {
    const float* x      = (const float*)d_in[0];
    const float* flux   = (const float*)d_in[1];
    const float* prompt = (const float*)d_in[2];
    const float* conv_w = (const float*)d_in[3];
    const float* b1w    = (const float*)d_in[4];
    const float* b1b    = (const float*)d_in[5];
    const float* b2w    = (const float*)d_in[6];
    const float* b2b    = (const float*)d_in[7];
    const float* t1w    = (const float*)d_in[8];
    const float* t1b    = (const float*)d_in[9];
    const float* t2w    = (const float*)d_in[10];
    const float* t2b    = (const float*)d_in[11];
    float* out = (float*)d_out;

    // ws: c2 [6][524288] uint4 = 50,331,648 B ; WfB [14][8][64][8] bf16 = 114,688 B
    char* ws = (char*)d_ws;
    uint4* c2 = (uint4*)ws;
    unsigned short* WfB = (unsigned short*)(ws + (size_t)6 * NPIX * 16);

    fold_weights_kernel<<<224, 256, 0, stream>>>(conv_w, prompt, WfB);
    routing_kernel<<<1024, 256, 0, stream>>>(x, flux, b1w, b1b, b2w, b2b,
                                             t1w, t1b, t2w, t2b, c2);
    conv_kernel<<<4096, 256, 0, stream>>>(c2, WfB, out);
}

// Round 6
// 231.962 us; speedup vs baseline: 5.5571x; 5.5571x over previous
//
#include <hip/hip_runtime.h>
#include <hip/hip_bf16.h>
#include <math.h>

#define HW   65536   // 256*256
#define NPIX 524288  // 8*65536
#define NB   8
#define NT   6
#define NC   48      // nt*nb combined channels
#define DIM  64
#define EE   128
#define KSTEPS 14    // K = 9 taps * 48 ch = 432, padded to 448 = 14 * 32
#define KVALID 432
#define COLS 130

typedef short bf16x8 __attribute__((ext_vector_type(8)));
typedef float f32x4  __attribute__((ext_vector_type(4)));

__device__ __forceinline__ float gelu_exact(float v) {
    return 0.5f * v * (1.0f + erff(v * 0.70710678118654752f));
}

__device__ __forceinline__ unsigned pack_bf16(float v0, float v1) {
    __hip_bfloat16 h0 = __float2bfloat16(v0);
    __hip_bfloat16 h1 = __float2bfloat16(v1);
    return (unsigned)(*(unsigned short*)&h0) | ((unsigned)(*(unsigned short*)&h1) << 16);
}

// ---------------- Kernel A: fold prompt into conv weights, fragment-ordered bf16 ----
__global__ __launch_bounds__(256) void fold_weights_kernel(
    const float* __restrict__ conv_w,   // [128][128][3][3]
    const float* __restrict__ prompt,   // [6][8][128]
    unsigned short* __restrict__ WfB)   // [14][8][64][8] bf16
{
    int f = blockIdx.x * 256 + threadIdx.x;   // 0 .. 57343
    int j    = f & 7;
    int lane = (f >> 3) & 63;
    int ob   = (f >> 9) & 7;
    int ks   = f >> 12;

    int o = ob * 16 + (lane & 15);
    int k = ks * 32 + ((lane >> 4) << 3) + j;

    float acc = 0.f;
    if (k < KVALID) {
        int tap = k / 48;
        int tk  = k - tap * 48;
        int dy = tap / 3;
        int dx = tap - dy * 3;
        const float* pw = conv_w + ((size_t)o * EE) * 9 + dy * 3 + dx;
        const float* pp = prompt + (size_t)tk * EE;
        #pragma unroll 4
        for (int e = 0; e < EE; ++e)
            acc += pw[(size_t)e * 9] * pp[e];
    }
    __hip_bfloat16 h = __float2bfloat16(acc);
    WfB[f] = *(unsigned short*)&h;
}

// ---------------- Kernel B: routing -> c2[6 chunk][pixel] (uint4 = 8 bf16 ch) ----
// 2 pixels/thread, float2 loads, 8-deep register batches (unroll-1 outer loop
// -> no live-range replication, no spills), shuffle-redistributed 1KB stores.
__global__ __launch_bounds__(256) void routing_kernel(
    const float* __restrict__ x,      // [8][64][256][256]
    const float* __restrict__ flux,   // [8][128][256][256]
    const float* __restrict__ b1w, const float* __restrict__ b1b,
    const float* __restrict__ b2w, const float* __restrict__ b2b,
    const float* __restrict__ t1w, const float* __restrict__ t1b,
    const float* __restrict__ t2w, const float* __restrict__ t2b,
    uint4* __restrict__ c2)           // [6][NPIX] 16B chunks
{
    __shared__ float s_b1w[DIM * 8];   // [ci][j] transposed
    __shared__ float s_t1w[EE * 8];    // [ci][j] transposed, j<6 padded with 0
    __shared__ float s_b2w[64];
    __shared__ float s_t2w[36];
    __shared__ float s_b1b[8], s_b2b[8], s_t1b[8], s_t2b[8];

    int tid = threadIdx.x;
    for (int i = tid; i < DIM * 8; i += 256) {
        int ci = i >> 3, j = i & 7;
        s_b1w[i] = b1w[j * DIM + ci];
    }
    for (int i = tid; i < EE * 8; i += 256) {
        int ci = i >> 3, j = i & 7;
        s_t1w[i] = (j < NT) ? t1w[j * EE + ci] : 0.f;
    }
    if (tid < 64) s_b2w[tid] = b2w[tid];
    if (tid < 36) s_t2w[tid] = t2w[tid];
    if (tid < 8) {
        s_b1b[tid] = b1b[tid];
        s_b2b[tid] = b2b[tid];
        s_t1b[tid] = (tid < NT) ? t1b[tid] : 0.f;
        s_t2b[tid] = (tid < NT) ? t2b[tid] : 0.f;
    }
    __syncthreads();

    int gid = blockIdx.x * 256 + tid;      // 0 .. 262143 ; pixels 2*gid, 2*gid+1
    int b   = gid >> 15;
    int yx  = (gid << 1) & (HW - 1);

    // ---- MLP2 on flux (128 -> 6), nan->0, 2 pixels, 8-deep batches ----
    float t0[6], t1[6];
    #pragma unroll
    for (int j = 0; j < NT; ++j) { t0[j] = s_t1b[j]; t1[j] = s_t1b[j]; }
    const float* fp = flux + (size_t)b * EE * HW + yx;
    #pragma unroll 1
    for (int cb = 0; cb < EE; cb += 8) {
        float2 v[8];
        #pragma unroll
        for (int u = 0; u < 8; ++u)
            v[u] = *(const float2*)(fp + (size_t)(cb + u) * HW);
        #pragma unroll
        for (int u = 0; u < 8; ++u) {
            float v0 = v[u].x; v0 = (v0 == v0) ? v0 : 0.f;
            float v1 = v[u].y; v1 = (v1 == v1) ? v1 : 0.f;
            float4 wA = *(const float4*)&s_t1w[(cb + u) * 8];
            float2 wB = *(const float2*)&s_t1w[(cb + u) * 8 + 4];
            t0[0] += v0 * wA.x; t1[0] += v1 * wA.x;
            t0[1] += v0 * wA.y; t1[1] += v1 * wA.y;
            t0[2] += v0 * wA.z; t1[2] += v1 * wA.z;
            t0[3] += v0 * wA.w; t1[3] += v1 * wA.w;
            t0[4] += v0 * wB.x; t1[4] += v1 * wB.x;
            t0[5] += v0 * wB.y; t1[5] += v1 * wB.y;
        }
    }

    // ---- MLP1 on x (64 -> 8), 2 pixels, 8-deep batches ----
    float a0[8], a1[8];
    #pragma unroll
    for (int j = 0; j < 8; ++j) { a0[j] = s_b1b[j]; a1[j] = s_b1b[j]; }
    const float* xp = x + (size_t)b * DIM * HW + yx;
    #pragma unroll 1
    for (int cb = 0; cb < DIM; cb += 8) {
        float2 v[8];
        #pragma unroll
        for (int u = 0; u < 8; ++u)
            v[u] = *(const float2*)(xp + (size_t)(cb + u) * HW);
        #pragma unroll
        for (int u = 0; u < 8; ++u) {
            float v0 = v[u].x;
            float v1 = v[u].y;
            float4 wa = *(const float4*)&s_b1w[(cb + u) * 8];
            float4 wb = *(const float4*)&s_b1w[(cb + u) * 8 + 4];
            a0[0] += v0 * wa.x; a1[0] += v1 * wa.x;
            a0[1] += v0 * wa.y; a1[1] += v1 * wa.y;
            a0[2] += v0 * wa.z; a1[2] += v1 * wa.z;
            a0[3] += v0 * wa.w; a1[3] += v1 * wa.w;
            a0[4] += v0 * wb.x; a1[4] += v1 * wb.x;
            a0[5] += v0 * wb.y; a1[5] += v1 * wb.y;
            a0[6] += v0 * wb.z; a1[6] += v1 * wb.z;
            a0[7] += v0 * wb.w; a1[7] += v1 * wb.w;
        }
    }

    // ---- finish task (softmax over 6) for both pixels ----
    float task[2][6];
    #pragma unroll
    for (int p = 0; p < 2; ++p) {
        float gt[6];
        #pragma unroll
        for (int j = 0; j < NT; ++j) gt[j] = gelu_exact(p ? t1[j] : t0[j]);
        float tv[6];
        #pragma unroll
        for (int i = 0; i < NT; ++i) {
            float s = s_t2b[i];
            #pragma unroll
            for (int j = 0; j < NT; ++j) s += gt[j] * s_t2w[i * 6 + j];
            tv[i] = s;
        }
        float m = tv[0];
        #pragma unroll
        for (int i = 1; i < NT; ++i) m = fmaxf(m, tv[i]);
        float s = 0.f;
        #pragma unroll
        for (int i = 0; i < NT; ++i) { tv[i] = expf(tv[i] - m); s += tv[i]; }
        float inv = 1.f / s;
        #pragma unroll
        for (int i = 0; i < NT; ++i) task[p][i] = tv[i] * inv;
    }

    // ---- finish basis (softmax over 8) for both pixels ----
    float basis[2][8];
    #pragma unroll
    for (int p = 0; p < 2; ++p) {
        float g[8];
        #pragma unroll
        for (int j = 0; j < 8; ++j) g[j] = gelu_exact(p ? a1[j] : a0[j]);
        float bv[8];
        #pragma unroll
        for (int i = 0; i < 8; ++i) {
            float s = s_b2b[i];
            #pragma unroll
            for (int j = 0; j < 8; ++j) s += g[j] * s_b2w[i * 8 + j];
            bv[i] = s;
        }
        float m = bv[0];
        #pragma unroll
        for (int i = 1; i < 8; ++i) m = fmaxf(m, bv[i]);
        float s = 0.f;
        #pragma unroll
        for (int i = 0; i < 8; ++i) { bv[i] = expf(bv[i] - m); s += bv[i]; }
        float inv = 1.f / s;
        #pragma unroll
        for (int i = 0; i < 8; ++i) basis[p][i] = bv[i] * inv;
    }

    // ---- shuffle-redistribute so each store instruction is 1KB contiguous ----
    int lane = tid & 63;
    int srcA = lane >> 1;
    int srcB = 32 + (lane >> 1);
    bool odd = lane & 1;

    float tA[6], tB[6], bA[8], bB[8];
    #pragma unroll
    for (int j = 0; j < NT; ++j) {
        float p0 = __shfl(task[0][j], srcA, 64);
        float p1 = __shfl(task[1][j], srcA, 64);
        tA[j] = odd ? p1 : p0;
        float q0 = __shfl(task[0][j], srcB, 64);
        float q1 = __shfl(task[1][j], srcB, 64);
        tB[j] = odd ? q1 : q0;
    }
    #pragma unroll
    for (int k = 0; k < 8; ++k) {
        float p0 = __shfl(basis[0][k], srcA, 64);
        float p1 = __shfl(basis[1][k], srcA, 64);
        bA[k] = odd ? p1 : p0;
        float q0 = __shfl(basis[0][k], srcB, 64);
        float q1 = __shfl(basis[1][k], srcB, 64);
        bB[k] = odd ? q1 : q0;
    }

    int wbase = (gid & ~63) * 2;    // wave's first pixel
    #pragma unroll
    for (int j = 0; j < 6; ++j) {
        uint4 qa, qb;
        qa.x = pack_bf16(tA[j] * bA[0], tA[j] * bA[1]);
        qa.y = pack_bf16(tA[j] * bA[2], tA[j] * bA[3]);
        qa.z = pack_bf16(tA[j] * bA[4], tA[j] * bA[5]);
        qa.w = pack_bf16(tA[j] * bA[6], tA[j] * bA[7]);
        qb.x = pack_bf16(tB[j] * bB[0], tB[j] * bB[1]);
        qb.y = pack_bf16(tB[j] * bB[2], tB[j] * bB[3]);
        qb.z = pack_bf16(tB[j] * bB[4], tB[j] * bB[5]);
        qb.w = pack_bf16(tB[j] * bB[6], tB[j] * bB[7]);
        c2[(size_t)j * NPIX + wbase + lane]      = qa;
        c2[(size_t)j * NPIX + wbase + 64 + lane] = qb;
    }
}

// ---------------- Kernel C: implicit-GEMM 3x3 conv via bf16 MFMA, K=448 ----------------
__global__ __launch_bounds__(256, 3) void conv_kernel(
    const uint4* __restrict__ c2,           // [6][NPIX] 16B chunks
    const unsigned short* __restrict__ WfB, // [14][8][64][8] bf16 fragment-ordered
    float* __restrict__ out)                // [8][128][256][256] f32
{
    __shared__ uint4 tile4[3120];   // [3][130][64ch] bf16, XOR-swizzled (49,920 B)

    int bid = blockIdx.x;
    int s = bid & 1;
    int y = (bid >> 1) & 255;
    int b = bid >> 9;
    int x0 = s << 7;
    int tid = threadIdx.x;

    // zero-fill (covers ch 48..63 padding and image borders)
    #pragma unroll 4
    for (int i = tid; i < 3120; i += 256)
        tile4[i] = make_uint4(0u, 0u, 0u, 0u);
    __syncthreads();

    // stage c halo tile: 3 rows x 6 chunks x 130 cols (col innermost -> coalesced)
    for (int idx = tid; idx < 2340; idx += 256) {
        int dyc = idx / 130;
        int col = idx - dyc * 130;
        int dy  = dyc / 6;
        int ch  = dyc - dy * 6;
        int gy = y + dy - 1;
        int gx = x0 - 1 + col;
        if ((unsigned)gy < 256u && (unsigned)gx < 256u) {
            uint4 v = c2[(size_t)ch * NPIX + (((size_t)b << 16) + (gy << 8) + gx)];
            int lb = ((dy * COLS + col) << 7) + (ch << 4);
            lb ^= (col & 7) << 4;
            tile4[lb >> 4] = v;
        }
    }
    __syncthreads();

    int lane = tid & 63;
    int wv = tid >> 6;
    int wm = wv & 1;
    int wn = wv >> 1;
    int o0 = wm << 6;
    int nbase = wn << 2;          // N-group base (of 16-pixel groups)
    int lrow = lane & 15;         // m (for A/D) and n (for B/D)
    int lk   = lane >> 4;         // k sub-block

    f32x4 acc[4][4];
    #pragma unroll
    for (int mi = 0; mi < 4; ++mi)
        #pragma unroll
        for (int ni = 0; ni < 4; ++ni)
            acc[mi][ni] = (f32x4){0.f, 0.f, 0.f, 0.f};

    const char* tbase = (const char*)tile4;

    #pragma unroll
    for (int ks = 0; ks < KSTEPS; ++ks) {
        bf16x8 a[4];
        #pragma unroll
        for (int mi = 0; mi < 4; ++mi)
            a[mi] = *(const bf16x8*)(WfB + ((size_t)((ks * 8) + wm * 4 + mi) * 64 + lane) * 8);

        // k0 = ks*32 + lk*8 ; tap = k0/48 (clamped), ch = k0 - tap*48
        int k0 = ks * 32 + (lk << 3);
        int tap = k0 / 48;
        if (tap > 8) tap = 8;        // k>=432 pad: lands in zeroed ch48..63 region
        int ch = k0 - tap * 48;
        int dy = tap / 3;
        int dx = tap - dy * 3;

        #pragma unroll
        for (int ni = 0; ni < 4; ++ni) {
            int col = ((nbase + ni) << 4) + lrow + dx;
            int lb = ((dy * COLS + col) << 7) + (ch << 1);
            lb ^= (col & 7) << 4;
            bf16x8 bfr = *(const bf16x8*)(tbase + lb);
            #pragma unroll
            for (int mi = 0; mi < 4; ++mi)
                acc[mi][ni] = __builtin_amdgcn_mfma_f32_16x16x32_bf16(a[mi], bfr, acc[mi][ni], 0, 0, 0);
        }
    }

    // D layout: col = lane&15 (pixel), row = (lane>>4)*4 + r (out channel)
    int orow = lk << 2;
    #pragma unroll
    for (int mi = 0; mi < 4; ++mi) {
        #pragma unroll
        for (int ni = 0; ni < 4; ++ni) {
            int o = o0 + mi * 16 + orow;
            int xx = x0 + ((nbase + ni) << 4) + lrow;
            float* op = out + (((size_t)(b * 128 + o)) << 16) + (y << 8) + xx;
            #pragma unroll
            for (int r = 0; r < 4; ++r)
                op[(size_t)r << 16] = acc[mi][ni][r];
        }
    }
}

extern "C" void kernel_launch(void* const* d_in, const int* in_sizes, int n_in,
                              void* d_out, int out_size, void* d_ws, size_t ws_size,
                              hipStream_t stream) {
    const float* x      = (const float*)d_in[0];
    const float* flux   = (const float*)d_in[1];
    const float* prompt = (const float*)d_in[2];
    const float* conv_w = (const float*)d_in[3];
    const float* b1w    = (const float*)d_in[4];
    const float* b1b    = (const float*)d_in[5];
    const float* b2w    = (const float*)d_in[6];
    const float* b2b    = (const float*)d_in[7];
    const float* t1w    = (const float*)d_in[8];
    const float* t1b    = (const float*)d_in[9];
    const float* t2w    = (const float*)d_in[10];
    const float* t2b    = (const float*)d_in[11];
    float* out = (float*)d_out;

    // ws: c2 [6][524288] uint4 = 50,331,648 B ; WfB [14][8][64][8] bf16 = 114,688 B
    char* ws = (char*)d_ws;
    uint4* c2 = (uint4*)ws;
    unsigned short* WfB = (unsigned short*)(ws + (size_t)6 * NPIX * 16);

    fold_weights_kernel<<<224, 256, 0, stream>>>(conv_w, prompt, WfB);
    routing_kernel<<<1024, 256, 0, stream>>>(x, flux, b1w, b1b, b2w, b2b,
                                             t1w, t1b, t2w, t2b, c2);
    conv_kernel<<<4096, 256, 0, stream>>>(c2, WfB, out);
}